// Round 1
// baseline (289.774 us; speedup 1.0000x reference)
//
#include <hip/hip_runtime.h>

typedef unsigned short u16;
typedef unsigned int u32;
typedef __bf16 bf16x8 __attribute__((ext_vector_type(8)));
typedef float f32x4 __attribute__((ext_vector_type(4)));

#define CC 768
#define TT 2560
#define NH 12
#define HD 64
#define KDIM 768

__device__ __forceinline__ u16 f2bf(float f) {
  u32 u = __builtin_bit_cast(u32, f);
  u32 r = u + 0x7fffu + ((u >> 16) & 1u);
  return (u16)(r >> 16);
}

// ---------------- fp32 -> bf16 convert ----------------
__global__ void convk(const float* __restrict__ in, u16* __restrict__ out, int n4) {
  int i = blockIdx.x * blockDim.x + threadIdx.x;
  if (i >= n4) return;
  float4 v = ((const float4*)in)[i];
  ushort4 o;
  o.x = f2bf(v.x); o.y = f2bf(v.y); o.z = f2bf(v.z); o.w = f2bf(v.w);
  ((ushort4*)out)[i] = o;
}

// ---------------- QKV projection GEMM ----------------
// C[m,n] = sum_k A[m,k] * W[n,k]  (A = x bf16 [5120][768], W bf16 [768][768])
// z=0 -> q [B,H,T,64]; z=1 -> k [B,H,T,64]; z=2 -> v^T [B,H,64,T]
__global__ __launch_bounds__(256) void gemm_qkv(
    const u16* __restrict__ xb,
    const u16* __restrict__ wqb, const u16* __restrict__ wkb, const u16* __restrict__ wvb,
    const float* __restrict__ bq, const float* __restrict__ bk, const float* __restrict__ bv,
    u16* __restrict__ qo, u16* __restrict__ ko, u16* __restrict__ vo)
{
  __shared__ __align__(16) u16 lds_a[128 * 72];
  __shared__ __align__(16) u16 lds_b[128 * 72];
  int z = blockIdx.z;
  const u16* W = (z == 0) ? wqb : (z == 1 ? wkb : wvb);
  const float* bias = (z == 0) ? bq : (z == 1 ? bk : bv);
  int n0 = blockIdx.x * 128;
  int m0 = blockIdx.y * 128;
  int tid = threadIdx.x;
  int lane = tid & 63, wv_ = tid >> 6;
  int wm = wv_ & 1, wn = wv_ >> 1;
  int mcol = lane & 15, quad = lane >> 4;
  int chunk = tid & 7, rbase = tid >> 3;

  f32x4 acc[4][4] = {};

  for (int k0 = 0; k0 < KDIM; k0 += 64) {
    __syncthreads();
#pragma unroll
    for (int r = 0; r < 4; ++r) {
      int row = rbase + r * 32;
      *(uint4*)&lds_a[row * 72 + chunk * 8] =
          *(const uint4*)&xb[(size_t)(m0 + row) * KDIM + k0 + chunk * 8];
      *(uint4*)&lds_b[row * 72 + chunk * 8] =
          *(const uint4*)&W[(size_t)(n0 + row) * KDIM + k0 + chunk * 8];
    }
    __syncthreads();
#pragma unroll
    for (int kc = 0; kc < 2; ++kc) {
      bf16x8 af[4], bfr[4];
#pragma unroll
      for (int i = 0; i < 4; i++)
        af[i] = *(const bf16x8*)&lds_a[(wm * 64 + i * 16 + mcol) * 72 + kc * 32 + quad * 8];
#pragma unroll
      for (int i = 0; i < 4; i++)
        bfr[i] = *(const bf16x8*)&lds_b[(wn * 64 + i * 16 + mcol) * 72 + kc * 32 + quad * 8];
#pragma unroll
      for (int i = 0; i < 4; i++)
#pragma unroll
        for (int j = 0; j < 4; j++)
          acc[i][j] = __builtin_amdgcn_mfma_f32_16x16x32_bf16(af[i], bfr[j], acc[i][j], 0, 0, 0);
    }
  }

#pragma unroll
  for (int i = 0; i < 4; i++) {
    int rowb = m0 + wm * 64 + i * 16 + quad * 4;
    int b = rowb / TT;
    int tt0 = rowb - b * TT;
#pragma unroll
    for (int j = 0; j < 4; j++) {
      int col = n0 + wn * 64 + j * 16 + mcol;
      int h = col >> 6, d = col & 63;
      float bb_ = bias[col];
      if (z == 2) {
        ushort4 pk;
        pk.x = f2bf(acc[i][j][0] + bb_);
        pk.y = f2bf(acc[i][j][1] + bb_);
        pk.z = f2bf(acc[i][j][2] + bb_);
        pk.w = f2bf(acc[i][j][3] + bb_);
        *(ushort4*)&vo[((size_t)(b * NH + h) * HD + d) * TT + tt0] = pk;
      } else {
        u16* dst = (z == 0) ? qo : ko;
#pragma unroll
        for (int r = 0; r < 4; r++)
          dst[((size_t)(b * NH + h) * TT + tt0 + r) * HD + d] = f2bf(acc[i][j][r] + bb_);
      }
    }
  }
}

// ---------------- fused masked attention (flash-style) ----------------
// grid (T/64, B*H), 256 thr (4 waves x 16 q-rows). mask: (i%256) >= (j%256)
__global__ __launch_bounds__(256) void attn(
    const u16* __restrict__ q, const u16* __restrict__ k,
    const u16* __restrict__ vt, u16* __restrict__ y)
{
  __shared__ __align__(16) u16 lds_k[128 * 72];
  __shared__ __align__(16) u16 lds_vt[64 * 136];
  __shared__ __align__(16) u16 lds_p[4][16 * 136];

  int tid = threadIdx.x;
  int lane = tid & 63, w = tid >> 6;
  int mcol = lane & 15, quad = lane >> 4;
  int qb = blockIdx.x;
  int bh = blockIdx.y;
  int b = bh / NH, h = bh - b * NH;
  const u16* qp = q + (size_t)bh * TT * HD;
  const u16* kp = k + (size_t)bh * TT * HD;
  const u16* vp = vt + (size_t)bh * HD * TT;

  int qrow0 = qb * 64 + w * 16;
  int qhalf = (qrow0 >> 7) & 1;
  int iibase = (qrow0 & 127) + quad * 4;

  bf16x8 qf[2];
#pragma unroll
  for (int c = 0; c < 2; c++)
    qf[c] = *(const bf16x8*)&qp[(size_t)(qrow0 + mcol) * HD + c * 32 + quad * 8];

  const f32x4 z4 = {0.f, 0.f, 0.f, 0.f};
  float m_i[4], l_i[4];
  f32x4 o[4] = {};
#pragma unroll
  for (int r2 = 0; r2 < 4; r2++) { m_i[r2] = -1e30f; l_i[r2] = 0.f; }

  const float lscale = 0.125f * 1.44269504088896f; // 1/sqrt(64) * log2(e)

  int chunk = tid & 7, rbase = tid >> 3;
  int cg = tid & 15, d0 = tid >> 4;

  for (int kt = 0; kt < 20; ++kt) {
    int khalf = kt & 1;
    if (khalf > qhalf) continue; // whole tile masked for this q-block (uniform)
    __syncthreads();
#pragma unroll
    for (int r2 = 0; r2 < 4; ++r2) {
      int row = rbase + r2 * 32;
      *(uint4*)&lds_k[row * 72 + chunk * 8] =
          *(const uint4*)&kp[(size_t)(kt * 128 + row) * HD + chunk * 8];
      int d = d0 + r2 * 16;
      *(uint4*)&lds_vt[d * 136 + cg * 8] =
          *(const uint4*)&vp[(size_t)d * TT + kt * 128 + cg * 8];
    }
    __syncthreads();

    // S = Q K^T  (16 x 128 per wave)
    f32x4 s[8];
#pragma unroll
    for (int nf = 0; nf < 8; ++nf) {
      s[nf] = z4;
#pragma unroll
      for (int kc = 0; kc < 2; ++kc) {
        bf16x8 kf = *(const bf16x8*)&lds_k[(nf * 16 + mcol) * 72 + kc * 32 + quad * 8];
        s[nf] = __builtin_amdgcn_mfma_f32_16x16x32_bf16(qf[kc], kf, s[nf], 0, 0, 0);
      }
    }

    bool need_mask = (khalf == qhalf);
    float tmax[4] = {-1e30f, -1e30f, -1e30f, -1e30f};
#pragma unroll
    for (int nf = 0; nf < 8; ++nf) {
      int jj = nf * 16 + mcol;
#pragma unroll
      for (int r2 = 0; r2 < 4; ++r2) {
        float v = s[nf][r2] * lscale;
        if (need_mask && (jj > iibase + r2)) v = -1e30f;
        s[nf][r2] = v;
        tmax[r2] = fmaxf(tmax[r2], v);
      }
    }
#pragma unroll
    for (int off = 1; off < 16; off <<= 1)
#pragma unroll
      for (int r2 = 0; r2 < 4; ++r2)
        tmax[r2] = fmaxf(tmax[r2], __shfl_xor(tmax[r2], off, 64));

    float alpha[4], rsum[4];
#pragma unroll
    for (int r2 = 0; r2 < 4; ++r2) {
      float nm = fmaxf(m_i[r2], tmax[r2]);
      alpha[r2] = exp2f(m_i[r2] - nm);
      m_i[r2] = nm;
      rsum[r2] = 0.f;
    }
#pragma unroll
    for (int nf = 0; nf < 8; ++nf)
#pragma unroll
      for (int r2 = 0; r2 < 4; ++r2) {
        float p = exp2f(s[nf][r2] - m_i[r2]);
        s[nf][r2] = p;
        rsum[r2] += p;
      }
#pragma unroll
    for (int off = 1; off < 16; off <<= 1)
#pragma unroll
      for (int r2 = 0; r2 < 4; ++r2)
        rsum[r2] += __shfl_xor(rsum[r2], off, 64);
#pragma unroll
    for (int r2 = 0; r2 < 4; ++r2)
      l_i[r2] = l_i[r2] * alpha[r2] + rsum[r2];
#pragma unroll
    for (int df = 0; df < 4; ++df)
#pragma unroll
      for (int r2 = 0; r2 < 4; ++r2)
        o[df][r2] *= alpha[r2];

    // P: C-layout -> A-layout via per-wave LDS
#pragma unroll
    for (int nf = 0; nf < 8; ++nf)
#pragma unroll
      for (int r2 = 0; r2 < 4; ++r2)
        lds_p[w][(quad * 4 + r2) * 136 + nf * 16 + mcol] = f2bf(s[nf][r2]);
    __syncthreads();

    // O += P V
#pragma unroll
    for (int kc = 0; kc < 4; ++kc) {
      bf16x8 pf = *(const bf16x8*)&lds_p[w][mcol * 136 + kc * 32 + quad * 8];
#pragma unroll
      for (int df = 0; df < 4; ++df) {
        bf16x8 vf = *(const bf16x8*)&lds_vt[(df * 16 + mcol) * 136 + kc * 32 + quad * 8];
        o[df] = __builtin_amdgcn_mfma_f32_16x16x32_bf16(pf, vf, o[df], 0, 0, 0);
      }
    }
  }

  // write y [B,T,C] bf16
#pragma unroll
  for (int df = 0; df < 4; ++df) {
#pragma unroll
    for (int r2 = 0; r2 < 4; ++r2) {
      int qrow = qrow0 + quad * 4 + r2;
      float val = o[df][r2] / l_i[r2];
      y[((size_t)(b * TT + qrow)) * CC + h * HD + df * 16 + mcol] = f2bf(val);
    }
  }
}

// ---------------- output projection GEMM ----------------
__global__ __launch_bounds__(256) void gemm_out(
    const u16* __restrict__ yb, const u16* __restrict__ wpb,
    const float* __restrict__ bp, float* __restrict__ out)
{
  __shared__ __align__(16) u16 lds_a[128 * 72];
  __shared__ __align__(16) u16 lds_b[128 * 72];
  int n0 = blockIdx.x * 128;
  int m0 = blockIdx.y * 128;
  int tid = threadIdx.x;
  int lane = tid & 63, wv_ = tid >> 6;
  int wm = wv_ & 1, wn = wv_ >> 1;
  int mcol = lane & 15, quad = lane >> 4;
  int chunk = tid & 7, rbase = tid >> 3;

  f32x4 acc[4][4] = {};

  for (int k0 = 0; k0 < KDIM; k0 += 64) {
    __syncthreads();
#pragma unroll
    for (int r = 0; r < 4; ++r) {
      int row = rbase + r * 32;
      *(uint4*)&lds_a[row * 72 + chunk * 8] =
          *(const uint4*)&yb[(size_t)(m0 + row) * KDIM + k0 + chunk * 8];
      *(uint4*)&lds_b[row * 72 + chunk * 8] =
          *(const uint4*)&wpb[(size_t)(n0 + row) * KDIM + k0 + chunk * 8];
    }
    __syncthreads();
#pragma unroll
    for (int kc = 0; kc < 2; ++kc) {
      bf16x8 af[4], bfr[4];
#pragma unroll
      for (int i = 0; i < 4; i++)
        af[i] = *(const bf16x8*)&lds_a[(wm * 64 + i * 16 + mcol) * 72 + kc * 32 + quad * 8];
#pragma unroll
      for (int i = 0; i < 4; i++)
        bfr[i] = *(const bf16x8*)&lds_b[(wn * 64 + i * 16 + mcol) * 72 + kc * 32 + quad * 8];
#pragma unroll
      for (int i = 0; i < 4; i++)
#pragma unroll
        for (int j = 0; j < 4; j++)
          acc[i][j] = __builtin_amdgcn_mfma_f32_16x16x32_bf16(af[i], bfr[j], acc[i][j], 0, 0, 0);
    }
  }

#pragma unroll
  for (int i = 0; i < 4; i++) {
    int row0 = m0 + wm * 64 + i * 16 + quad * 4;
#pragma unroll
    for (int j = 0; j < 4; j++) {
      int col = n0 + wn * 64 + j * 16 + mcol;
      float bb_ = bp[col];
#pragma unroll
      for (int r = 0; r < 4; r++)
        out[(size_t)(row0 + r) * CC + col] = acc[i][j][r] + bb_;
    }
  }
}

extern "C" void kernel_launch(void* const* d_in, const int* in_sizes, int n_in,
                              void* d_out, int out_size, void* d_ws, size_t ws_size,
                              hipStream_t stream) {
  const float* x  = (const float*)d_in[0];
  const float* Wk = (const float*)d_in[1];
  const float* bk = (const float*)d_in[2];
  const float* Wq = (const float*)d_in[3];
  const float* bq = (const float*)d_in[4];
  const float* Wv = (const float*)d_in[5];
  const float* bv = (const float*)d_in[6];
  const float* Wp = (const float*)d_in[7];
  const float* bp = (const float*)d_in[8];
  float* out = (float*)d_out;

  char* ws = (char*)d_ws;
  size_t off = 0;
  auto alloc = [&](size_t bytes) {
    void* p = ws + off;
    off += (bytes + 255) & ~(size_t)255;
    return p;
  };
  const size_t NX = (size_t)2 * TT * CC;   // 3932160
  const size_t NW = (size_t)CC * CC;       // 589824
  u16* xb  = (u16*)alloc(NX * 2);
  u16* wqb = (u16*)alloc(NW * 2);
  u16* wkb = (u16*)alloc(NW * 2);
  u16* wvb = (u16*)alloc(NW * 2);
  u16* wpb = (u16*)alloc(NW * 2);
  u16* qws = (u16*)alloc(NX * 2);
  u16* kws = (u16*)alloc(NX * 2);
  u16* vtw = (u16*)alloc(NX * 2);
  u16* yws = (u16*)alloc(NX * 2);

  int nx4 = (int)(NX / 4), nw4 = (int)(NW / 4);
  convk<<<(nx4 + 255) / 256, 256, 0, stream>>>(x, xb, nx4);
  convk<<<(nw4 + 255) / 256, 256, 0, stream>>>(Wq, wqb, nw4);
  convk<<<(nw4 + 255) / 256, 256, 0, stream>>>(Wk, wkb, nw4);
  convk<<<(nw4 + 255) / 256, 256, 0, stream>>>(Wv, wvb, nw4);
  convk<<<(nw4 + 255) / 256, 256, 0, stream>>>(Wp, wpb, nw4);

  gemm_qkv<<<dim3(6, 40, 3), 256, 0, stream>>>(xb, wqb, wkb, wvb, bq, bk, bv,
                                               qws, kws, vtw);
  attn<<<dim3(40, 24), 256, 0, stream>>>(qws, kws, vtw, yws);
  gemm_out<<<dim3(6, 40), 256, 0, stream>>>(yws, wpb, bp, out);
}

// Round 2
// 272.361 us; speedup vs baseline: 1.0639x; 1.0639x over previous
//
#include <hip/hip_runtime.h>

typedef unsigned short u16;
typedef unsigned int u32;
typedef __bf16 bf16x8 __attribute__((ext_vector_type(8)));
typedef float f32x4 __attribute__((ext_vector_type(4)));

#define CC 768
#define TT 2560
#define NH 12
#define HD 64
#define KDIM 768

// 1/sqrt(64) * log2(e) -- folded into q in the QKV GEMM epilogue
#define QSCALE 0.18033688011112042f

__device__ __forceinline__ u16 f2bf(float f) {
  u32 u = __builtin_bit_cast(u32, f);
  u32 r = u + 0x7fffu + ((u >> 16) & 1u);
  return (u16)(r >> 16);
}

// ---------------- fused fp32 -> bf16 converts (1 launch) ----------------
__global__ void convall(const float* __restrict__ x,
                        const float* __restrict__ Wq, const float* __restrict__ Wk,
                        const float* __restrict__ Wv, const float* __restrict__ Wp,
                        u16* __restrict__ xb, u16* __restrict__ wqb, u16* __restrict__ wkb,
                        u16* __restrict__ wvb, u16* __restrict__ wpb,
                        int nx4, int nw4) {
  int z = blockIdx.y;
  const float* in; u16* out; int n4;
  switch (z) {
    case 0: in = x;  out = xb;  n4 = nx4; break;
    case 1: in = Wq; out = wqb; n4 = nw4; break;
    case 2: in = Wk; out = wkb; n4 = nw4; break;
    case 3: in = Wv; out = wvb; n4 = nw4; break;
    default: in = Wp; out = wpb; n4 = nw4; break;
  }
  int i = blockIdx.x * blockDim.x + threadIdx.x;
  if (i >= n4) return;
  float4 v = ((const float4*)in)[i];
  ushort4 o;
  o.x = f2bf(v.x); o.y = f2bf(v.y); o.z = f2bf(v.z); o.w = f2bf(v.w);
  ((ushort4*)out)[i] = o;
}

// ---------------- QKV projection GEMM ----------------
// z=0 -> q*QSCALE [B,H,T,64]; z=1 -> k [B,H,T,64]; z=2 -> v^T [B,H,64,T]
__global__ __launch_bounds__(256) void gemm_qkv(
    const u16* __restrict__ xb,
    const u16* __restrict__ wqb, const u16* __restrict__ wkb, const u16* __restrict__ wvb,
    const float* __restrict__ bq, const float* __restrict__ bk, const float* __restrict__ bv,
    u16* __restrict__ qo, u16* __restrict__ ko, u16* __restrict__ vo)
{
  __shared__ __align__(16) u16 lds_a[128 * 72];
  __shared__ __align__(16) u16 lds_b[128 * 72];
  int z = blockIdx.z;
  const u16* W = (z == 0) ? wqb : (z == 1 ? wkb : wvb);
  const float* bias = (z == 0) ? bq : (z == 1 ? bk : bv);
  int n0 = blockIdx.x * 128;
  int m0 = blockIdx.y * 128;
  int tid = threadIdx.x;
  int lane = tid & 63, wv_ = tid >> 6;
  int wm = wv_ & 1, wn = wv_ >> 1;
  int mcol = lane & 15, quad = lane >> 4;
  int chunk = tid & 7, rbase = tid >> 3;

  f32x4 acc[4][4] = {};

  for (int k0 = 0; k0 < KDIM; k0 += 64) {
    __syncthreads();
#pragma unroll
    for (int r = 0; r < 4; ++r) {
      int row = rbase + r * 32;
      *(uint4*)&lds_a[row * 72 + chunk * 8] =
          *(const uint4*)&xb[(size_t)(m0 + row) * KDIM + k0 + chunk * 8];
      *(uint4*)&lds_b[row * 72 + chunk * 8] =
          *(const uint4*)&W[(size_t)(n0 + row) * KDIM + k0 + chunk * 8];
    }
    __syncthreads();
#pragma unroll
    for (int kc = 0; kc < 2; ++kc) {
      bf16x8 af[4], bfr[4];
#pragma unroll
      for (int i = 0; i < 4; i++)
        af[i] = *(const bf16x8*)&lds_a[(wm * 64 + i * 16 + mcol) * 72 + kc * 32 + quad * 8];
#pragma unroll
      for (int i = 0; i < 4; i++)
        bfr[i] = *(const bf16x8*)&lds_b[(wn * 64 + i * 16 + mcol) * 72 + kc * 32 + quad * 8];
#pragma unroll
      for (int i = 0; i < 4; i++)
#pragma unroll
        for (int j = 0; j < 4; j++)
          acc[i][j] = __builtin_amdgcn_mfma_f32_16x16x32_bf16(af[i], bfr[j], acc[i][j], 0, 0, 0);
    }
  }

  float scale = (z == 0) ? QSCALE : 1.0f;
#pragma unroll
  for (int i = 0; i < 4; i++) {
    int rowb = m0 + wm * 64 + i * 16 + quad * 4;
    int b = rowb / TT;
    int tt0 = rowb - b * TT;
#pragma unroll
    for (int j = 0; j < 4; j++) {
      int col = n0 + wn * 64 + j * 16 + mcol;
      int h = col >> 6, d = col & 63;
      float bb_ = bias[col];
      if (z == 2) {
        ushort4 pk;
        pk.x = f2bf(acc[i][j][0] + bb_);
        pk.y = f2bf(acc[i][j][1] + bb_);
        pk.z = f2bf(acc[i][j][2] + bb_);
        pk.w = f2bf(acc[i][j][3] + bb_);
        *(ushort4*)&vo[((size_t)(b * NH + h) * HD + d) * TT + tt0] = pk;
      } else {
        u16* dst = (z == 0) ? qo : ko;
#pragma unroll
        for (int r = 0; r < 4; r++)
          dst[((size_t)(b * NH + h) * TT + tt0 + r) * HD + d] = f2bf((acc[i][j][r] + bb_) * scale);
      }
    }
  }
}

// ---------------- fused masked attention (S^T orientation, fixed m=0) -------
// grid (T/64, B*H), 256 thr (4 waves x 16 q-rows). mask: (i%256) >= (j%256)
__global__ __launch_bounds__(256) void attn(
    const u16* __restrict__ q, const u16* __restrict__ k,
    const u16* __restrict__ vt, u16* __restrict__ y)
{
  __shared__ __align__(16) u16 lds_k[128 * 72];
  __shared__ __align__(16) u16 lds_vt[64 * 136];
  __shared__ __align__(16) u16 lds_pt[4][16 * 136];

  int tid = threadIdx.x;
  int lane = tid & 63, w = tid >> 6;
  int mcol = lane & 15, quad = lane >> 4;
  int qb = blockIdx.x;
  int bh = blockIdx.y;
  int b = bh / NH, h = bh - b * NH;
  const u16* qp = q + (size_t)bh * TT * HD;
  const u16* kp = k + (size_t)bh * TT * HD;
  const u16* vp = vt + (size_t)bh * HD * TT;

  int qrow0 = qb * 64 + w * 16;
  int qhalf = (qrow0 >> 7) & 1;
  int rlocal = qrow0 & 127;            // multiple of 16
  int ngrp_diag = (rlocal >> 4) + 1;   // key 16-groups alive on diagonal tiles
  int stage_diag = (qb & 1) ? 128 : 64;

  // Q fragment: q already pre-scaled by QSCALE in GEMM
  bf16x8 qf[2];
#pragma unroll
  for (int c = 0; c < 2; c++)
    qf[c] = *(const bf16x8*)&qp[(size_t)(qrow0 + mcol) * HD + c * 32 + quad * 8];

  float rsum = 0.f;
  f32x4 o[4] = {};

  int chunk = tid & 7, rbase = tid >> 3;
  int cg = tid & 15, d0 = tid >> 4;
  u16* ptw = &lds_pt[w][0];

  for (int kt = 0; kt < 20; ++kt) {
    int khalf = kt & 1;
    if (khalf > qhalf) continue;       // whole tile masked (block-uniform)
    bool diag = (khalf == qhalf);
    int stage_lim = diag ? stage_diag : 128;
    __syncthreads();
#pragma unroll
    for (int r2 = 0; r2 < 4; ++r2) {
      int row = rbase + r2 * 32;
      if (row < stage_lim)
        *(uint4*)&lds_k[row * 72 + chunk * 8] =
            *(const uint4*)&kp[(size_t)(kt * 128 + row) * HD + chunk * 8];
    }
    if (cg * 8 < stage_lim) {
#pragma unroll
      for (int r2 = 0; r2 < 4; ++r2) {
        int d = d0 + r2 * 16;
        *(uint4*)&lds_vt[d * 136 + cg * 8] =
            *(const uint4*)&vp[(size_t)d * TT + kt * 128 + cg * 8];
      }
    }
    __syncthreads();

    int ngrp = diag ? ngrp_diag : 8;
    int nfull = diag ? (ngrp - 1) : 8;

    // full (unmasked) key groups
    for (int g = 0; g < nfull; ++g) {
      f32x4 st = {0.f, 0.f, 0.f, 0.f};
#pragma unroll
      for (int kc = 0; kc < 2; ++kc) {
        bf16x8 kf = *(const bf16x8*)&lds_k[(g * 16 + mcol) * 72 + kc * 32 + quad * 8];
        st = __builtin_amdgcn_mfma_f32_16x16x32_bf16(kf, qf[kc], st, 0, 0, 0);
      }
      float p0 = __builtin_amdgcn_exp2f(st[0]);
      float p1 = __builtin_amdgcn_exp2f(st[1]);
      float p2 = __builtin_amdgcn_exp2f(st[2]);
      float p3 = __builtin_amdgcn_exp2f(st[3]);
      rsum += (p0 + p1) + (p2 + p3);
      u32 b0 = __builtin_bit_cast(u32, p0) + 0x8000u;
      u32 b1 = __builtin_bit_cast(u32, p1) + 0x8000u;
      u32 b2 = __builtin_bit_cast(u32, p2) + 0x8000u;
      u32 b3 = __builtin_bit_cast(u32, p3) + 0x8000u;
      uint2 pk;
      pk.x = __builtin_amdgcn_perm(b1, b0, 0x07060302u);
      pk.y = __builtin_amdgcn_perm(b3, b2, 0x07060302u);
      *(uint2*)&ptw[mcol * 136 + g * 16 + quad * 4] = pk;
    }

    // diagonal (partially masked) group
    if (diag) {
      int g = ngrp - 1;
      f32x4 st = {0.f, 0.f, 0.f, 0.f};
#pragma unroll
      for (int kc = 0; kc < 2; ++kc) {
        bf16x8 kf = *(const bf16x8*)&lds_k[(g * 16 + mcol) * 72 + kc * 32 + quad * 8];
        st = __builtin_amdgcn_mfma_f32_16x16x32_bf16(kf, qf[kc], st, 0, 0, 0);
      }
      int ii = rlocal + mcol;
      int jj = g * 16 + quad * 4;
      float p0 = (jj + 0 > ii) ? 0.f : __builtin_amdgcn_exp2f(st[0]);
      float p1 = (jj + 1 > ii) ? 0.f : __builtin_amdgcn_exp2f(st[1]);
      float p2 = (jj + 2 > ii) ? 0.f : __builtin_amdgcn_exp2f(st[2]);
      float p3 = (jj + 3 > ii) ? 0.f : __builtin_amdgcn_exp2f(st[3]);
      rsum += (p0 + p1) + (p2 + p3);
      u32 b0 = __builtin_bit_cast(u32, p0) + 0x8000u;
      u32 b1 = __builtin_bit_cast(u32, p1) + 0x8000u;
      u32 b2 = __builtin_bit_cast(u32, p2) + 0x8000u;
      u32 b3 = __builtin_bit_cast(u32, p3) + 0x8000u;
      uint2 pk;
      pk.x = __builtin_amdgcn_perm(b1, b0, 0x07060302u);
      pk.y = __builtin_amdgcn_perm(b3, b2, 0x07060302u);
      *(uint2*)&ptw[mcol * 136 + g * 16 + quad * 4] = pk;
      if (ngrp & 1) {
        uint2 zz; zz.x = 0u; zz.y = 0u;
        *(uint2*)&ptw[mcol * 136 + ngrp * 16 + quad * 4] = zz;  // zero pad group
      }
    }

    // O^T += V^T P^T   (A = V^T rows d, B = P^T)
    int kcc = diag ? ((ngrp + 1) >> 1) : 4;
    for (int kc = 0; kc < kcc; ++kc) {
      bf16x8 pf = *(const bf16x8*)&ptw[mcol * 136 + kc * 32 + quad * 8];
#pragma unroll
      for (int df = 0; df < 4; ++df) {
        bf16x8 vf = *(const bf16x8*)&lds_vt[(df * 16 + mcol) * 136 + kc * 32 + quad * 8];
        o[df] = __builtin_amdgcn_mfma_f32_16x16x32_bf16(vf, pf, o[df], 0, 0, 0);
      }
    }
  }

  // final row-sum reduce across the 4 quads holding the same q-row
  rsum += __shfl_xor(rsum, 16, 64);
  rsum += __shfl_xor(rsum, 32, 64);
  float inv = 1.0f / rsum;

  // write y [B,T,C] bf16; lane holds 4 consecutive d per df
  size_t yrow = ((size_t)(b * TT + qrow0 + mcol)) * CC + h * HD;
#pragma unroll
  for (int df = 0; df < 4; ++df) {
    ushort4 pk;
    pk.x = f2bf(o[df][0] * inv);
    pk.y = f2bf(o[df][1] * inv);
    pk.z = f2bf(o[df][2] * inv);
    pk.w = f2bf(o[df][3] * inv);
    *(ushort4*)&y[yrow + df * 16 + quad * 4] = pk;
  }
}

// ---------------- output projection GEMM ----------------
__global__ __launch_bounds__(256) void gemm_out(
    const u16* __restrict__ yb, const u16* __restrict__ wpb,
    const float* __restrict__ bp, float* __restrict__ out)
{
  __shared__ __align__(16) u16 lds_a[128 * 72];
  __shared__ __align__(16) u16 lds_b[128 * 72];
  int n0 = blockIdx.x * 128;
  int m0 = blockIdx.y * 128;
  int tid = threadIdx.x;
  int lane = tid & 63, wv_ = tid >> 6;
  int wm = wv_ & 1, wn = wv_ >> 1;
  int mcol = lane & 15, quad = lane >> 4;
  int chunk = tid & 7, rbase = tid >> 3;

  f32x4 acc[4][4] = {};

  for (int k0 = 0; k0 < KDIM; k0 += 64) {
    __syncthreads();
#pragma unroll
    for (int r = 0; r < 4; ++r) {
      int row = rbase + r * 32;
      *(uint4*)&lds_a[row * 72 + chunk * 8] =
          *(const uint4*)&yb[(size_t)(m0 + row) * KDIM + k0 + chunk * 8];
      *(uint4*)&lds_b[row * 72 + chunk * 8] =
          *(const uint4*)&wpb[(size_t)(n0 + row) * KDIM + k0 + chunk * 8];
    }
    __syncthreads();
#pragma unroll
    for (int kc = 0; kc < 2; ++kc) {
      bf16x8 af[4], bfr[4];
#pragma unroll
      for (int i = 0; i < 4; i++)
        af[i] = *(const bf16x8*)&lds_a[(wm * 64 + i * 16 + mcol) * 72 + kc * 32 + quad * 8];
#pragma unroll
      for (int i = 0; i < 4; i++)
        bfr[i] = *(const bf16x8*)&lds_b[(wn * 64 + i * 16 + mcol) * 72 + kc * 32 + quad * 8];
#pragma unroll
      for (int i = 0; i < 4; i++)
#pragma unroll
        for (int j = 0; j < 4; j++)
          acc[i][j] = __builtin_amdgcn_mfma_f32_16x16x32_bf16(af[i], bfr[j], acc[i][j], 0, 0, 0);
    }
  }

#pragma unroll
  for (int i = 0; i < 4; i++) {
    int row0 = m0 + wm * 64 + i * 16 + quad * 4;
#pragma unroll
    for (int j = 0; j < 4; j++) {
      int col = n0 + wn * 64 + j * 16 + mcol;
      float bb_ = bp[col];
#pragma unroll
      for (int r = 0; r < 4; r++)
        out[(size_t)(row0 + r) * CC + col] = acc[i][j][r] + bb_;
    }
  }
}

extern "C" void kernel_launch(void* const* d_in, const int* in_sizes, int n_in,
                              void* d_out, int out_size, void* d_ws, size_t ws_size,
                              hipStream_t stream) {
  const float* x  = (const float*)d_in[0];
  const float* Wk = (const float*)d_in[1];
  const float* bk = (const float*)d_in[2];
  const float* Wq = (const float*)d_in[3];
  const float* bq = (const float*)d_in[4];
  const float* Wv = (const float*)d_in[5];
  const float* bv = (const float*)d_in[6];
  const float* Wp = (const float*)d_in[7];
  const float* bp = (const float*)d_in[8];
  float* out = (float*)d_out;

  char* ws = (char*)d_ws;
  size_t off = 0;
  auto alloc = [&](size_t bytes) {
    void* p = ws + off;
    off += (bytes + 255) & ~(size_t)255;
    return p;
  };
  const size_t NX = (size_t)2 * TT * CC;
  const size_t NW = (size_t)CC * CC;
  u16* xb  = (u16*)alloc(NX * 2);
  u16* wqb = (u16*)alloc(NW * 2);
  u16* wkb = (u16*)alloc(NW * 2);
  u16* wvb = (u16*)alloc(NW * 2);
  u16* wpb = (u16*)alloc(NW * 2);
  u16* qws = (u16*)alloc(NX * 2);
  u16* kws = (u16*)alloc(NX * 2);
  u16* vtw = (u16*)alloc(NX * 2);
  u16* yws = (u16*)alloc(NX * 2);

  int nx4 = (int)(NX / 4), nw4 = (int)(NW / 4);
  convall<<<dim3((nx4 + 255) / 256, 5), 256, 0, stream>>>(
      x, Wq, Wk, Wv, Wp, xb, wqb, wkb, wvb, wpb, nx4, nw4);

  gemm_qkv<<<dim3(6, 40, 3), 256, 0, stream>>>(xb, wqb, wkb, wvb, bq, bk, bv,
                                               qws, kws, vtw);
  attn<<<dim3(40, 24), 256, 0, stream>>>(qws, kws, vtw, yws);
  gemm_out<<<dim3(6, 40), 256, 0, stream>>>(yws, wpb, bp, out);
}

// Round 3
// 256.421 us; speedup vs baseline: 1.1301x; 1.0622x over previous
//
#include <hip/hip_runtime.h>

typedef unsigned short u16;
typedef unsigned int u32;
typedef __bf16 bf16x8 __attribute__((ext_vector_type(8)));
typedef short s16x4 __attribute__((ext_vector_type(4)));
typedef float f32x4 __attribute__((ext_vector_type(4)));

#define CC 768
#define TT 2560
#define NH 12
#define HD 64
#define KDIM 768

// 1/sqrt(64) * log2(e) -- folded into q in the QKV GEMM epilogue
#define QSCALE 0.18033688011112042f

__device__ __forceinline__ u16 f2bf(float f) {
  u32 u = __builtin_bit_cast(u32, f);
  u32 r = u + 0x7fffu + ((u >> 16) & 1u);
  return (u16)(r >> 16);
}

#if __has_builtin(__builtin_amdgcn_mfma_f32_16x16x16bf16_1k)
__device__ __forceinline__ f32x4 mfma16b(s16x4 a, s16x4 b, f32x4 c) {
  return __builtin_amdgcn_mfma_f32_16x16x16bf16_1k(a, b, c, 0, 0, 0);
}
#else
__device__ __forceinline__ f32x4 mfma16b(s16x4 a, s16x4 b, f32x4 c) {
  f32x4 d;
  asm volatile("v_mfma_f32_16x16x16_bf16 %0, %1, %2, %3\n\ts_nop 7\n\ts_nop 7"
               : "=v"(d) : "v"(a), "v"(b), "v"(c));
  return d;
}
#endif

// ---------------- fused fp32 -> bf16 converts (1 launch) ----------------
__global__ void convall(const float* __restrict__ x,
                        const float* __restrict__ Wq, const float* __restrict__ Wk,
                        const float* __restrict__ Wv, const float* __restrict__ Wp,
                        u16* __restrict__ xb, u16* __restrict__ wqb, u16* __restrict__ wkb,
                        u16* __restrict__ wvb, u16* __restrict__ wpb,
                        int nx4, int nw4) {
  int z = blockIdx.y;
  const float* in; u16* out; int n4;
  switch (z) {
    case 0: in = x;  out = xb;  n4 = nx4; break;
    case 1: in = Wq; out = wqb; n4 = nw4; break;
    case 2: in = Wk; out = wkb; n4 = nw4; break;
    case 3: in = Wv; out = wvb; n4 = nw4; break;
    default: in = Wp; out = wpb; n4 = nw4; break;
  }
  int i = blockIdx.x * blockDim.x + threadIdx.x;
  if (i >= n4) return;
  float4 v = ((const float4*)in)[i];
  ushort4 o;
  o.x = f2bf(v.x); o.y = f2bf(v.y); o.z = f2bf(v.z); o.w = f2bf(v.w);
  ((ushort4*)out)[i] = o;
}

// ---------------- QKV projection GEMM ----------------
// z=0 -> q*QSCALE [B,H,T,64]
// z=1 -> k grouped [B,H, T/16, 2(kc), 16(key%16), 32(d%32)]  (MFMA A-frag order)
// z=2 -> v grouped [B,H, T/16, 64(d), 16(key%16)]            (MFMA A-frag order, K=16)
__global__ __launch_bounds__(256) void gemm_qkv(
    const u16* __restrict__ xb,
    const u16* __restrict__ wqb, const u16* __restrict__ wkb, const u16* __restrict__ wvb,
    const float* __restrict__ bq, const float* __restrict__ bk, const float* __restrict__ bv,
    u16* __restrict__ qo, u16* __restrict__ ko, u16* __restrict__ vo)
{
  __shared__ __align__(16) u16 lds_a[128 * 72];
  __shared__ __align__(16) u16 lds_b[128 * 72];
  int z = blockIdx.z;
  const u16* W = (z == 0) ? wqb : (z == 1 ? wkb : wvb);
  const float* bias = (z == 0) ? bq : (z == 1 ? bk : bv);
  int n0 = blockIdx.x * 128;
  int m0 = blockIdx.y * 128;
  int tid = threadIdx.x;
  int lane = tid & 63, wv_ = tid >> 6;
  int wm = wv_ & 1, wn = wv_ >> 1;
  int mcol = lane & 15, quad = lane >> 4;
  int chunk = tid & 7, rbase = tid >> 3;

  f32x4 acc[4][4] = {};

  for (int k0 = 0; k0 < KDIM; k0 += 64) {
    __syncthreads();
#pragma unroll
    for (int r = 0; r < 4; ++r) {
      int row = rbase + r * 32;
      *(uint4*)&lds_a[row * 72 + chunk * 8] =
          *(const uint4*)&xb[(size_t)(m0 + row) * KDIM + k0 + chunk * 8];
      *(uint4*)&lds_b[row * 72 + chunk * 8] =
          *(const uint4*)&W[(size_t)(n0 + row) * KDIM + k0 + chunk * 8];
    }
    __syncthreads();
#pragma unroll
    for (int kc = 0; kc < 2; ++kc) {
      bf16x8 af[4], bfr[4];
#pragma unroll
      for (int i = 0; i < 4; i++)
        af[i] = *(const bf16x8*)&lds_a[(wm * 64 + i * 16 + mcol) * 72 + kc * 32 + quad * 8];
#pragma unroll
      for (int i = 0; i < 4; i++)
        bfr[i] = *(const bf16x8*)&lds_b[(wn * 64 + i * 16 + mcol) * 72 + kc * 32 + quad * 8];
#pragma unroll
      for (int i = 0; i < 4; i++)
#pragma unroll
        for (int j = 0; j < 4; j++)
          acc[i][j] = __builtin_amdgcn_mfma_f32_16x16x32_bf16(af[i], bfr[j], acc[i][j], 0, 0, 0);
    }
  }

#pragma unroll
  for (int i = 0; i < 4; i++) {
    int rowb = m0 + wm * 64 + i * 16 + quad * 4;
    int b = rowb / TT;
    int tt0 = rowb - b * TT;       // token (key), multiple of 4, tt0&15 == quad*4
#pragma unroll
    for (int j = 0; j < 4; j++) {
      int col = n0 + wn * 64 + j * 16 + mcol;
      int h = col >> 6, d = col & 63;
      float bb_ = bias[col];
      size_t bhoff = (size_t)(b * NH + h) * (TT * HD);
      if (z == 2) {
        // grouped V: bhoff + (key>>4)*1024 + d*16 + (key&15); 4 consecutive keys
        ushort4 pk;
        pk.x = f2bf(acc[i][j][0] + bb_);
        pk.y = f2bf(acc[i][j][1] + bb_);
        pk.z = f2bf(acc[i][j][2] + bb_);
        pk.w = f2bf(acc[i][j][3] + bb_);
        *(ushort4*)&vo[bhoff + (size_t)(tt0 >> 4) * 1024 + d * 16 + (tt0 & 15)] = pk;
      } else if (z == 1) {
        // grouped K: bhoff + (key>>4)*1024 + (d>>5)*512 + (key&15)*32 + (d&31)
        size_t base = bhoff + (size_t)(tt0 >> 4) * 1024 + (d >> 5) * 512 + (d & 31);
#pragma unroll
        for (int r = 0; r < 4; r++)
          ko[base + ((tt0 & 15) + r) * 32] = f2bf(acc[i][j][r] + bb_);
      } else {
#pragma unroll
        for (int r = 0; r < 4; r++)
          qo[bhoff + (size_t)(tt0 + r) * HD + d] = f2bf((acc[i][j][r] + bb_) * QSCALE);
      }
    }
  }
}

// ---------------- fused masked attention: no LDS, no barriers ----------------
// grid(960) 1-D XCD-swizzled; 256 thr = 4 waves x 16 q-rows; per-wave tile skip.
// S^T = K*Q^T via 16x16x32 (C: key=quad*4+r, qrow=mcol) feeds PV B-operand of
// 16x16x16 (B: k=quad*4+j, n=mcol) directly in-register. mask: (i%256)>=(j%256).
__global__ __launch_bounds__(256) void attn(
    const u16* __restrict__ q, const u16* __restrict__ kg,
    const u16* __restrict__ vg, u16* __restrict__ y)
{
  int tid = threadIdx.x;
  int lane = tid & 63, w = tid >> 6;
  int mcol = lane & 15, quad = lane >> 4;
  int gid = blockIdx.x;
  int c = gid & 7, rr = gid >> 3;
  int bh = c * 3 + (rr % 3);       // 3 bh per XCD -> K/V resident in 4MB L2
  int qb = rr / 3;
  int b = bh / NH, h = bh - b * NH;
  const u16* qp = q + (size_t)bh * TT * HD;
  const u16* kp = kg + (size_t)bh * TT * HD;
  const u16* vp = vg + (size_t)bh * TT * HD;

  int qrow0 = qb * 64 + w * 16;
  int qhalf = (qrow0 >> 7) & 1;
  int rlocal = qrow0 & 127;
  int ngrp_diag = (rlocal >> 4) + 1;
  int ii = rlocal + mcol;

  bf16x8 qf0 = *(const bf16x8*)&qp[(size_t)(qrow0 + mcol) * HD + quad * 8];
  bf16x8 qf1 = *(const bf16x8*)&qp[(size_t)(qrow0 + mcol) * HD + 32 + quad * 8];

  float rsum = 0.f;
  f32x4 o[4] = {};

  int koff = mcol * 32 + quad * 8;  // u16 offset within a K group (b128, coalesced)
  int voff = mcol * 16 + quad * 4;  // u16 offset within a V df-slab (b64, coalesced)

  for (int kt = 0; kt < 20; ++kt) {
    int khalf = kt & 1;
    if (khalf > qhalf) continue;    // fully masked tile (wave-uniform)
    bool diag = (khalf == qhalf);
    int ngrp = diag ? ngrp_diag : 8;
    const u16* ktb = kp + kt * (128 * HD);
    const u16* vtb = vp + kt * (128 * HD);

    for (int g = 0; g < ngrp; ++g) {
      bf16x8 kf0 = *(const bf16x8*)&ktb[g * 1024 + koff];
      bf16x8 kf1 = *(const bf16x8*)&ktb[g * 1024 + 512 + koff];
      f32x4 st = {0.f, 0.f, 0.f, 0.f};
      st = __builtin_amdgcn_mfma_f32_16x16x32_bf16(kf0, qf0, st, 0, 0, 0);
      st = __builtin_amdgcn_mfma_f32_16x16x32_bf16(kf1, qf1, st, 0, 0, 0);

      float p0, p1, p2, p3;
      if (diag && (g == ngrp - 1)) {
        int jj = g * 16 + quad * 4;
        p0 = (jj + 0 > ii) ? 0.f : __builtin_amdgcn_exp2f(st[0]);
        p1 = (jj + 1 > ii) ? 0.f : __builtin_amdgcn_exp2f(st[1]);
        p2 = (jj + 2 > ii) ? 0.f : __builtin_amdgcn_exp2f(st[2]);
        p3 = (jj + 3 > ii) ? 0.f : __builtin_amdgcn_exp2f(st[3]);
      } else {
        p0 = __builtin_amdgcn_exp2f(st[0]);
        p1 = __builtin_amdgcn_exp2f(st[1]);
        p2 = __builtin_amdgcn_exp2f(st[2]);
        p3 = __builtin_amdgcn_exp2f(st[3]);
      }
      rsum += (p0 + p1) + (p2 + p3);

      u32 b0 = __builtin_bit_cast(u32, p0) + 0x8000u;
      u32 b1 = __builtin_bit_cast(u32, p1) + 0x8000u;
      u32 b2 = __builtin_bit_cast(u32, p2) + 0x8000u;
      u32 b3 = __builtin_bit_cast(u32, p3) + 0x8000u;
      uint2 pk;
      pk.x = __builtin_amdgcn_perm(b1, b0, 0x07060302u);
      pk.y = __builtin_amdgcn_perm(b3, b2, 0x07060302u);
      s16x4 pf = __builtin_bit_cast(s16x4, pk);

#pragma unroll
      for (int df = 0; df < 4; ++df) {
        s16x4 vf = *(const s16x4*)&vtb[g * 1024 + df * 256 + voff];
        o[df] = mfma16b(vf, pf, o[df]);
      }
    }
  }

  // reduce row-sum across the 4 quads holding the same q-row
  rsum += __shfl_xor(rsum, 16, 64);
  rsum += __shfl_xor(rsum, 32, 64);
  float inv = 1.0f / rsum;

  // write y [B,T,C] bf16; o[df] rows are 4 consecutive d
  size_t yrow = ((size_t)(b * TT + qrow0 + mcol)) * CC + h * HD;
#pragma unroll
  for (int df = 0; df < 4; ++df) {
    ushort4 pk;
    pk.x = f2bf(o[df][0] * inv);
    pk.y = f2bf(o[df][1] * inv);
    pk.z = f2bf(o[df][2] * inv);
    pk.w = f2bf(o[df][3] * inv);
    *(ushort4*)&y[yrow + df * 16 + quad * 4] = pk;
  }
}

// ---------------- output projection GEMM ----------------
__global__ __launch_bounds__(256) void gemm_out(
    const u16* __restrict__ yb, const u16* __restrict__ wpb,
    const float* __restrict__ bp, float* __restrict__ out)
{
  __shared__ __align__(16) u16 lds_a[128 * 72];
  __shared__ __align__(16) u16 lds_b[128 * 72];
  int n0 = blockIdx.x * 128;
  int m0 = blockIdx.y * 128;
  int tid = threadIdx.x;
  int lane = tid & 63, wv_ = tid >> 6;
  int wm = wv_ & 1, wn = wv_ >> 1;
  int mcol = lane & 15, quad = lane >> 4;
  int chunk = tid & 7, rbase = tid >> 3;

  f32x4 acc[4][4] = {};

  for (int k0 = 0; k0 < KDIM; k0 += 64) {
    __syncthreads();
#pragma unroll
    for (int r = 0; r < 4; ++r) {
      int row = rbase + r * 32;
      *(uint4*)&lds_a[row * 72 + chunk * 8] =
          *(const uint4*)&yb[(size_t)(m0 + row) * KDIM + k0 + chunk * 8];
      *(uint4*)&lds_b[row * 72 + chunk * 8] =
          *(const uint4*)&wpb[(size_t)(n0 + row) * KDIM + k0 + chunk * 8];
    }
    __syncthreads();
#pragma unroll
    for (int kc = 0; kc < 2; ++kc) {
      bf16x8 af[4], bfr[4];
#pragma unroll
      for (int i = 0; i < 4; i++)
        af[i] = *(const bf16x8*)&lds_a[(wm * 64 + i * 16 + mcol) * 72 + kc * 32 + quad * 8];
#pragma unroll
      for (int i = 0; i < 4; i++)
        bfr[i] = *(const bf16x8*)&lds_b[(wn * 64 + i * 16 + mcol) * 72 + kc * 32 + quad * 8];
#pragma unroll
      for (int i = 0; i < 4; i++)
#pragma unroll
        for (int j = 0; j < 4; j++)
          acc[i][j] = __builtin_amdgcn_mfma_f32_16x16x32_bf16(af[i], bfr[j], acc[i][j], 0, 0, 0);
    }
  }

#pragma unroll
  for (int i = 0; i < 4; i++) {
    int row0 = m0 + wm * 64 + i * 16 + quad * 4;
#pragma unroll
    for (int j = 0; j < 4; j++) {
      int col = n0 + wn * 64 + j * 16 + mcol;
      float bb_ = bp[col];
#pragma unroll
      for (int r = 0; r < 4; r++)
        out[(size_t)(row0 + r) * CC + col] = acc[i][j][r] + bb_;
    }
  }
}

extern "C" void kernel_launch(void* const* d_in, const int* in_sizes, int n_in,
                              void* d_out, int out_size, void* d_ws, size_t ws_size,
                              hipStream_t stream) {
  const float* x  = (const float*)d_in[0];
  const float* Wk = (const float*)d_in[1];
  const float* bk = (const float*)d_in[2];
  const float* Wq = (const float*)d_in[3];
  const float* bq = (const float*)d_in[4];
  const float* Wv = (const float*)d_in[5];
  const float* bv = (const float*)d_in[6];
  const float* Wp = (const float*)d_in[7];
  const float* bp = (const float*)d_in[8];
  float* out = (float*)d_out;

  char* ws = (char*)d_ws;
  size_t off = 0;
  auto alloc = [&](size_t bytes) {
    void* p = ws + off;
    off += (bytes + 255) & ~(size_t)255;
    return p;
  };
  const size_t NX = (size_t)2 * TT * CC;
  const size_t NW = (size_t)CC * CC;
  u16* xb  = (u16*)alloc(NX * 2);
  u16* wqb = (u16*)alloc(NW * 2);
  u16* wkb = (u16*)alloc(NW * 2);
  u16* wvb = (u16*)alloc(NW * 2);
  u16* wpb = (u16*)alloc(NW * 2);
  u16* qws = (u16*)alloc(NX * 2);
  u16* kws = (u16*)alloc(NX * 2);
  u16* vgw = (u16*)alloc(NX * 2);
  u16* yws = (u16*)alloc(NX * 2);

  int nx4 = (int)(NX / 4), nw4 = (int)(NW / 4);
  convall<<<dim3((nx4 + 255) / 256, 5), 256, 0, stream>>>(
      x, Wq, Wk, Wv, Wp, xb, wqb, wkb, wvb, wpb, nx4, nw4);

  gemm_qkv<<<dim3(6, 40, 3), 256, 0, stream>>>(xb, wqb, wkb, wvb, bq, bk, bv,
                                               qws, kws, vgw);
  attn<<<dim3(960), 256, 0, stream>>>(qws, kws, vgw, yws);
  gemm_out<<<dim3(6, 40), 256, 0, stream>>>(yws, wpb, bp, out);
}

// Round 4
// 218.325 us; speedup vs baseline: 1.3273x; 1.1745x over previous
//
#include <hip/hip_runtime.h>

typedef unsigned short u16;
typedef unsigned int u32;
typedef __bf16 bf16x8 __attribute__((ext_vector_type(8)));
typedef short s16x4 __attribute__((ext_vector_type(4)));
typedef float f32x4 __attribute__((ext_vector_type(4)));

#define CC 768
#define TT 2560
#define NH 12
#define HD 64
#define KDIM 768

// 1/sqrt(64) * log2(e) -- folded into q in the QKV GEMM epilogue
#define QSCALE 0.18033688011112042f

__device__ __forceinline__ u16 f2bf(float f) {
  u32 u = __builtin_bit_cast(u32, f);
  u32 r = u + 0x7fffu + ((u >> 16) & 1u);
  return (u16)(r >> 16);
}

#if __has_builtin(__builtin_amdgcn_mfma_f32_16x16x16bf16_1k)
__device__ __forceinline__ f32x4 mfma16b(s16x4 a, s16x4 b, f32x4 c) {
  return __builtin_amdgcn_mfma_f32_16x16x16bf16_1k(a, b, c, 0, 0, 0);
}
#else
__device__ __forceinline__ f32x4 mfma16b(s16x4 a, s16x4 b, f32x4 c) {
  f32x4 d;
  asm("v_mfma_f32_16x16x16_bf16 %0, %1, %2, %3\n\ts_nop 7\n\ts_nop 7"
      : "=v"(d) : "v"(a), "v"(b), "v"(c));
  return d;
}
#endif

// ---------------- fused fp32 -> bf16 converts (1 launch) ----------------
__global__ void convall(const float* __restrict__ x,
                        const float* __restrict__ Wq, const float* __restrict__ Wk,
                        const float* __restrict__ Wv, const float* __restrict__ Wp,
                        u16* __restrict__ xb, u16* __restrict__ wqb, u16* __restrict__ wkb,
                        u16* __restrict__ wvb, u16* __restrict__ wpb,
                        int nx4, int nw4) {
  int z = blockIdx.y;
  const float* in; u16* out; int n4;
  switch (z) {
    case 0: in = x;  out = xb;  n4 = nx4; break;
    case 1: in = Wq; out = wqb; n4 = nw4; break;
    case 2: in = Wk; out = wkb; n4 = nw4; break;
    case 3: in = Wv; out = wvb; n4 = nw4; break;
    default: in = Wp; out = wpb; n4 = nw4; break;
  }
  int i = blockIdx.x * blockDim.x + threadIdx.x;
  if (i >= n4) return;
  float4 v = ((const float4*)in)[i];
  ushort4 o;
  o.x = f2bf(v.x); o.y = f2bf(v.y); o.z = f2bf(v.z); o.w = f2bf(v.w);
  ((ushort4*)out)[i] = o;
}

// ---------------- QKV projection GEMM ----------------
// z=0 -> q*QSCALE [B,H,T,64]
// z=1 -> k grouped [B,H, T/16, 2(kc), 16(key%16), 32(d%32)]  (MFMA A-frag order)
// z=2 -> v grouped [B,H, T/16, 64(d), 16(key%16)]            (MFMA A-frag order, K=16)
__global__ __launch_bounds__(256) void gemm_qkv(
    const u16* __restrict__ xb,
    const u16* __restrict__ wqb, const u16* __restrict__ wkb, const u16* __restrict__ wvb,
    const float* __restrict__ bq, const float* __restrict__ bk, const float* __restrict__ bv,
    u16* __restrict__ qo, u16* __restrict__ ko, u16* __restrict__ vo)
{
  __shared__ __align__(16) u16 lds_a[128 * 72];
  __shared__ __align__(16) u16 lds_b[128 * 72];
  int z = blockIdx.z;
  const u16* W = (z == 0) ? wqb : (z == 1 ? wkb : wvb);
  const float* bias = (z == 0) ? bq : (z == 1 ? bk : bv);
  int n0 = blockIdx.x * 128;
  int m0 = blockIdx.y * 128;
  int tid = threadIdx.x;
  int lane = tid & 63, wv_ = tid >> 6;
  int wm = wv_ & 1, wn = wv_ >> 1;
  int mcol = lane & 15, quad = lane >> 4;
  int chunk = tid & 7, rbase = tid >> 3;

  f32x4 acc[4][4] = {};

  for (int k0 = 0; k0 < KDIM; k0 += 64) {
    __syncthreads();
#pragma unroll
    for (int r = 0; r < 4; ++r) {
      int row = rbase + r * 32;
      *(uint4*)&lds_a[row * 72 + chunk * 8] =
          *(const uint4*)&xb[(size_t)(m0 + row) * KDIM + k0 + chunk * 8];
      *(uint4*)&lds_b[row * 72 + chunk * 8] =
          *(const uint4*)&W[(size_t)(n0 + row) * KDIM + k0 + chunk * 8];
    }
    __syncthreads();
#pragma unroll
    for (int kc = 0; kc < 2; ++kc) {
      bf16x8 af[4], bfr[4];
#pragma unroll
      for (int i = 0; i < 4; i++)
        af[i] = *(const bf16x8*)&lds_a[(wm * 64 + i * 16 + mcol) * 72 + kc * 32 + quad * 8];
#pragma unroll
      for (int i = 0; i < 4; i++)
        bfr[i] = *(const bf16x8*)&lds_b[(wn * 64 + i * 16 + mcol) * 72 + kc * 32 + quad * 8];
#pragma unroll
      for (int i = 0; i < 4; i++)
#pragma unroll
        for (int j = 0; j < 4; j++)
          acc[i][j] = __builtin_amdgcn_mfma_f32_16x16x32_bf16(af[i], bfr[j], acc[i][j], 0, 0, 0);
    }
  }

#pragma unroll
  for (int i = 0; i < 4; i++) {
    int rowb = m0 + wm * 64 + i * 16 + quad * 4;
    int b = rowb / TT;
    int tt0 = rowb - b * TT;       // token (key), multiple of 4, tt0&15 == quad*4
#pragma unroll
    for (int j = 0; j < 4; j++) {
      int col = n0 + wn * 64 + j * 16 + mcol;
      int h = col >> 6, d = col & 63;
      float bb_ = bias[col];
      size_t bhoff = (size_t)(b * NH + h) * (TT * HD);
      if (z == 2) {
        ushort4 pk;
        pk.x = f2bf(acc[i][j][0] + bb_);
        pk.y = f2bf(acc[i][j][1] + bb_);
        pk.z = f2bf(acc[i][j][2] + bb_);
        pk.w = f2bf(acc[i][j][3] + bb_);
        *(ushort4*)&vo[bhoff + (size_t)(tt0 >> 4) * 1024 + d * 16 + (tt0 & 15)] = pk;
      } else if (z == 1) {
        size_t base = bhoff + (size_t)(tt0 >> 4) * 1024 + (d >> 5) * 512 + (d & 31);
#pragma unroll
        for (int r = 0; r < 4; r++)
          ko[base + ((tt0 & 15) + r) * 32] = f2bf(acc[i][j][r] + bb_);
      } else {
#pragma unroll
        for (int r = 0; r < 4; r++)
          qo[bhoff + (size_t)(tt0 + r) * HD + d] = f2bf((acc[i][j][r] + bb_) * QSCALE);
      }
    }
  }
}

// ---------------- fused masked attention: 4 strips/wave, balanced ------------
// 960 blocks x 64 thr (1 wave). Wave handles 4 q-strips of 16 rows in one
// 512-row span: light (q%256<128) at local r, heavy at local 7-r. Every wave
// does exactly 34 strip-groups per kt-pair; K/V fragment loads shared by all
// 4 strips (4 independent MFMA chains hide latency). No LDS, no barriers.
struct Strip {
  bf16x8 qf0, qf1;
  f32x4 o0, o1, o2, o3;
  f32x4 racc;   // ones-row MFMA accumulator: racc[0] = softmax denominator
};

__device__ __forceinline__ void strip_step(
    Strip& S, bf16x8 kf0, bf16x8 kf1,
    s16x4 vf0, s16x4 vf1, s16x4 vf2, s16x4 vf3,
    bool maskg, int mcol, int quad)
{
  f32x4 st = {0.f, 0.f, 0.f, 0.f};
  st = __builtin_amdgcn_mfma_f32_16x16x32_bf16(kf0, S.qf0, st, 0, 0, 0);
  st = __builtin_amdgcn_mfma_f32_16x16x32_bf16(kf1, S.qf1, st, 0, 0, 0);
  float p0 = __builtin_amdgcn_exp2f(st[0]);
  float p1 = __builtin_amdgcn_exp2f(st[1]);
  float p2 = __builtin_amdgcn_exp2f(st[2]);
  float p3 = __builtin_amdgcn_exp2f(st[3]);
  if (maskg) {
    int j0 = quad * 4;
    p0 = (j0 + 0 > mcol) ? 0.f : p0;
    p1 = (j0 + 1 > mcol) ? 0.f : p1;
    p2 = (j0 + 2 > mcol) ? 0.f : p2;
    p3 = (j0 + 3 > mcol) ? 0.f : p3;
  }
  u32 b0 = __builtin_bit_cast(u32, p0) + 0x8000u;
  u32 b1 = __builtin_bit_cast(u32, p1) + 0x8000u;
  u32 b2 = __builtin_bit_cast(u32, p2) + 0x8000u;
  u32 b3 = __builtin_bit_cast(u32, p3) + 0x8000u;
  uint2 pk;
  pk.x = __builtin_amdgcn_perm(b1, b0, 0x07060302u);
  pk.y = __builtin_amdgcn_perm(b3, b2, 0x07060302u);
  s16x4 pf = __builtin_bit_cast(s16x4, pk);
  const s16x4 ones = {0x3F80, 0x3F80, 0x3F80, 0x3F80};  // bf16 1.0 x4
  S.racc = mfma16b(ones, pf, S.racc);
  S.o0 = mfma16b(vf0, pf, S.o0);
  S.o1 = mfma16b(vf1, pf, S.o1);
  S.o2 = mfma16b(vf2, pf, S.o2);
  S.o3 = mfma16b(vf3, pf, S.o3);
}

__global__ __launch_bounds__(64) void attn(
    const u16* __restrict__ q, const u16* __restrict__ kg,
    const u16* __restrict__ vg, u16* __restrict__ y)
{
  int lane = threadIdx.x & 63;
  int mcol = lane & 15, quad = lane >> 4;
  int gid = blockIdx.x;
  int c = gid & 7;              // XCD (round-robin dispatch heuristic)
  int idx = gid >> 3;           // 0..119
  int sub = idx / 40;           // 0..2  -> 3 bh per XCD (K/V resident in L2)
  int s = idx - sub * 40;       // 0..39
  int bh = c * 3 + sub;
  int hb = s >> 3;              // 0..4  (512-row span)
  int r = s & 7;                // light local strip; heavy local = 7-r
  int b = bh / NH, h = bh - b * NH;
  const u16* qp = q + (size_t)bh * TT * HD;
  const u16* kp = kg + (size_t)bh * TT * HD;
  const u16* vp = vg + (size_t)bh * TT * HD;

  int base = hb * 512;
  int rh = 7 - r;
  int qr[4];
  qr[0] = base + r * 16;              // L1 (half 0 of 256-tile)
  qr[1] = base + 128 + rh * 16;       // H1 (half 1)
  qr[2] = base + 256 + r * 16;        // L2
  qr[3] = base + 384 + rh * 16;       // H2

  Strip S[4];
#pragma unroll
  for (int i = 0; i < 4; ++i) {
    S[i].qf0 = *(const bf16x8*)&qp[(size_t)(qr[i] + mcol) * HD + quad * 8];
    S[i].qf1 = *(const bf16x8*)&qp[(size_t)(qr[i] + mcol) * HD + 32 + quad * 8];
    S[i].o0 = {0.f, 0.f, 0.f, 0.f};
    S[i].o1 = {0.f, 0.f, 0.f, 0.f};
    S[i].o2 = {0.f, 0.f, 0.f, 0.f};
    S[i].o3 = {0.f, 0.f, 0.f, 0.f};
    S[i].racc = {0.f, 0.f, 0.f, 0.f};
  }

  int koff = mcol * 32 + quad * 8;  // u16 offset in K group (b128, coalesced)
  int voff = mcol * 16 + quad * 4;  // u16 offset in V df-slab (b64, coalesced)

  for (int kt = 0; kt < 20; ++kt) {
    const u16* ktb = kp + kt * (128 * HD);
    const u16* vtb = vp + kt * (128 * HD);
    if ((kt & 1) == 0) {
      // even tile: heavy strips full 8 groups; light strips groups 0..r
#pragma unroll
      for (int g = 0; g < 8; ++g) {
        bf16x8 kf0 = *(const bf16x8*)&ktb[g * 1024 + koff];
        bf16x8 kf1 = *(const bf16x8*)&ktb[g * 1024 + 512 + koff];
        s16x4 vf0 = *(const s16x4*)&vtb[g * 1024 + 0 * 256 + voff];
        s16x4 vf1 = *(const s16x4*)&vtb[g * 1024 + 1 * 256 + voff];
        s16x4 vf2 = *(const s16x4*)&vtb[g * 1024 + 2 * 256 + voff];
        s16x4 vf3 = *(const s16x4*)&vtb[g * 1024 + 3 * 256 + voff];
        strip_step(S[1], kf0, kf1, vf0, vf1, vf2, vf3, false, mcol, quad);
        strip_step(S[3], kf0, kf1, vf0, vf1, vf2, vf3, false, mcol, quad);
        if (g <= r) {
          bool mg = (g == r);
          strip_step(S[0], kf0, kf1, vf0, vf1, vf2, vf3, mg, mcol, quad);
          strip_step(S[2], kf0, kf1, vf0, vf1, vf2, vf3, mg, mcol, quad);
        }
      }
    } else {
      // odd tile: heavy strips groups 0..rh (partial at rh); light strips skip
      for (int g = 0; g <= rh; ++g) {
        bf16x8 kf0 = *(const bf16x8*)&ktb[g * 1024 + koff];
        bf16x8 kf1 = *(const bf16x8*)&ktb[g * 1024 + 512 + koff];
        s16x4 vf0 = *(const s16x4*)&vtb[g * 1024 + 0 * 256 + voff];
        s16x4 vf1 = *(const s16x4*)&vtb[g * 1024 + 1 * 256 + voff];
        s16x4 vf2 = *(const s16x4*)&vtb[g * 1024 + 2 * 256 + voff];
        s16x4 vf3 = *(const s16x4*)&vtb[g * 1024 + 3 * 256 + voff];
        bool mg = (g == rh);
        strip_step(S[1], kf0, kf1, vf0, vf1, vf2, vf3, mg, mcol, quad);
        strip_step(S[3], kf0, kf1, vf0, vf1, vf2, vf3, mg, mcol, quad);
      }
    }
  }

  // epilogue: divide by denominator (racc[0], identical across quads) + store
#pragma unroll
  for (int i = 0; i < 4; ++i) {
    float inv = 1.0f / S[i].racc[0];
    size_t yrow = ((size_t)(b * TT + qr[i] + mcol)) * CC + h * HD;
    f32x4 oo[4] = {S[i].o0, S[i].o1, S[i].o2, S[i].o3};
#pragma unroll
    for (int df = 0; df < 4; ++df) {
      ushort4 pk;
      pk.x = f2bf(oo[df][0] * inv);
      pk.y = f2bf(oo[df][1] * inv);
      pk.z = f2bf(oo[df][2] * inv);
      pk.w = f2bf(oo[df][3] * inv);
      *(ushort4*)&y[yrow + df * 16 + quad * 4] = pk;
    }
  }
}

// ---------------- output projection GEMM ----------------
__global__ __launch_bounds__(256) void gemm_out(
    const u16* __restrict__ yb, const u16* __restrict__ wpb,
    const float* __restrict__ bp, float* __restrict__ out)
{
  __shared__ __align__(16) u16 lds_a[128 * 72];
  __shared__ __align__(16) u16 lds_b[128 * 72];
  int n0 = blockIdx.x * 128;
  int m0 = blockIdx.y * 128;
  int tid = threadIdx.x;
  int lane = tid & 63, wv_ = tid >> 6;
  int wm = wv_ & 1, wn = wv_ >> 1;
  int mcol = lane & 15, quad = lane >> 4;
  int chunk = tid & 7, rbase = tid >> 3;

  f32x4 acc[4][4] = {};

  for (int k0 = 0; k0 < KDIM; k0 += 64) {
    __syncthreads();
#pragma unroll
    for (int r = 0; r < 4; ++r) {
      int row = rbase + r * 32;
      *(uint4*)&lds_a[row * 72 + chunk * 8] =
          *(const uint4*)&yb[(size_t)(m0 + row) * KDIM + k0 + chunk * 8];
      *(uint4*)&lds_b[row * 72 + chunk * 8] =
          *(const uint4*)&wpb[(size_t)(n0 + row) * KDIM + k0 + chunk * 8];
    }
    __syncthreads();
#pragma unroll
    for (int kc = 0; kc < 2; ++kc) {
      bf16x8 af[4], bfr[4];
#pragma unroll
      for (int i = 0; i < 4; i++)
        af[i] = *(const bf16x8*)&lds_a[(wm * 64 + i * 16 + mcol) * 72 + kc * 32 + quad * 8];
#pragma unroll
      for (int i = 0; i < 4; i++)
        bfr[i] = *(const bf16x8*)&lds_b[(wn * 64 + i * 16 + mcol) * 72 + kc * 32 + quad * 8];
#pragma unroll
      for (int i = 0; i < 4; i++)
#pragma unroll
        for (int j = 0; j < 4; j++)
          acc[i][j] = __builtin_amdgcn_mfma_f32_16x16x32_bf16(af[i], bfr[j], acc[i][j], 0, 0, 0);
    }
  }

#pragma unroll
  for (int i = 0; i < 4; i++) {
    int row0 = m0 + wm * 64 + i * 16 + quad * 4;
#pragma unroll
    for (int j = 0; j < 4; j++) {
      int col = n0 + wn * 64 + j * 16 + mcol;
      float bb_ = bp[col];
#pragma unroll
      for (int r = 0; r < 4; r++)
        out[(size_t)(row0 + r) * CC + col] = acc[i][j][r] + bb_;
    }
  }
}

extern "C" void kernel_launch(void* const* d_in, const int* in_sizes, int n_in,
                              void* d_out, int out_size, void* d_ws, size_t ws_size,
                              hipStream_t stream) {
  const float* x  = (const float*)d_in[0];
  const float* Wk = (const float*)d_in[1];
  const float* bk = (const float*)d_in[2];
  const float* Wq = (const float*)d_in[3];
  const float* bq = (const float*)d_in[4];
  const float* Wv = (const float*)d_in[5];
  const float* bv = (const float*)d_in[6];
  const float* Wp = (const float*)d_in[7];
  const float* bp = (const float*)d_in[8];
  float* out = (float*)d_out;

  char* ws = (char*)d_ws;
  size_t off = 0;
  auto alloc = [&](size_t bytes) {
    void* p = ws + off;
    off += (bytes + 255) & ~(size_t)255;
    return p;
  };
  const size_t NX = (size_t)2 * TT * CC;
  const size_t NW = (size_t)CC * CC;
  u16* xb  = (u16*)alloc(NX * 2);
  u16* wqb = (u16*)alloc(NW * 2);
  u16* wkb = (u16*)alloc(NW * 2);
  u16* wvb = (u16*)alloc(NW * 2);
  u16* wpb = (u16*)alloc(NW * 2);
  u16* qws = (u16*)alloc(NX * 2);
  u16* kws = (u16*)alloc(NX * 2);
  u16* vgw = (u16*)alloc(NX * 2);
  u16* yws = (u16*)alloc(NX * 2);

  int nx4 = (int)(NX / 4), nw4 = (int)(NW / 4);
  convall<<<dim3((nx4 + 255) / 256, 5), 256, 0, stream>>>(
      x, Wq, Wk, Wv, Wp, xb, wqb, wkb, wvb, wpb, nx4, nw4);

  gemm_qkv<<<dim3(6, 40, 3), 256, 0, stream>>>(xb, wqb, wkb, wvb, bq, bk, bv,
                                               qws, kws, vgw);
  attn<<<dim3(960), 64, 0, stream>>>(qws, kws, vgw, yws);
  gemm_out<<<dim3(6, 40), 256, 0, stream>>>(yws, wpb, bp, out);
}

// Round 5
// 193.412 us; speedup vs baseline: 1.4982x; 1.1288x over previous
//
#include <hip/hip_runtime.h>

typedef unsigned short u16;
typedef unsigned int u32;
typedef __bf16 bf16x8 __attribute__((ext_vector_type(8)));
typedef short s16x4 __attribute__((ext_vector_type(4)));
typedef float f32x4 __attribute__((ext_vector_type(4)));

#define CC 768
#define TT 2560
#define NH 12
#define HD 64
#define KDIM 768

// 1/sqrt(64) * log2(e) -- folded into q in the QKV GEMM epilogue
#define QSCALE 0.18033688011112042f

__device__ __forceinline__ u16 f2bf(float f) {
  u32 u = __builtin_bit_cast(u32, f);
  u32 r = u + 0x7fffu + ((u >> 16) & 1u);
  return (u16)(r >> 16);
}

#if __has_builtin(__builtin_amdgcn_mfma_f32_16x16x16bf16_1k)
__device__ __forceinline__ f32x4 mfma16b(s16x4 a, s16x4 b, f32x4 c) {
  return __builtin_amdgcn_mfma_f32_16x16x16bf16_1k(a, b, c, 0, 0, 0);
}
#else
__device__ __forceinline__ f32x4 mfma16b(s16x4 a, s16x4 b, f32x4 c) {
  f32x4 d;
  asm("v_mfma_f32_16x16x16_bf16 %0, %1, %2, %3\n\ts_nop 7\n\ts_nop 7"
      : "=v"(d) : "v"(a), "v"(b), "v"(c));
  return d;
}
#endif

// ---------------- fused fp32 -> bf16 converts (1 launch) ----------------
__global__ void convall(const float* __restrict__ x,
                        const float* __restrict__ Wq, const float* __restrict__ Wk,
                        const float* __restrict__ Wv, const float* __restrict__ Wp,
                        u16* __restrict__ xb, u16* __restrict__ wqb, u16* __restrict__ wkb,
                        u16* __restrict__ wvb, u16* __restrict__ wpb,
                        int nx4, int nw4) {
  int z = blockIdx.y;
  const float* in; u16* out; int n4;
  switch (z) {
    case 0: in = x;  out = xb;  n4 = nx4; break;
    case 1: in = Wq; out = wqb; n4 = nw4; break;
    case 2: in = Wk; out = wkb; n4 = nw4; break;
    case 3: in = Wv; out = wvb; n4 = nw4; break;
    default: in = Wp; out = wpb; n4 = nw4; break;
  }
  int i = blockIdx.x * blockDim.x + threadIdx.x;
  if (i >= n4) return;
  float4 v = ((const float4*)in)[i];
  ushort4 o;
  o.x = f2bf(v.x); o.y = f2bf(v.y); o.z = f2bf(v.z); o.w = f2bf(v.w);
  ((ushort4*)out)[i] = o;
}

// ---------------- QKV projection GEMM ----------------
// z=0 -> q*QSCALE [B,H,T,64]
// z=1 -> k grouped [B,H, T/16, 2(kc), 16(key%16), 32(d%32)]  (MFMA A-frag order)
// z=2 -> v grouped [B,H, T/16, 64(d), 16(key%16)]            (MFMA A-frag order, K=16)
__global__ __launch_bounds__(256) void gemm_qkv(
    const u16* __restrict__ xb,
    const u16* __restrict__ wqb, const u16* __restrict__ wkb, const u16* __restrict__ wvb,
    const float* __restrict__ bq, const float* __restrict__ bk, const float* __restrict__ bv,
    u16* __restrict__ qo, u16* __restrict__ ko, u16* __restrict__ vo)
{
  __shared__ __align__(16) u16 lds_a[128 * 72];
  __shared__ __align__(16) u16 lds_b[128 * 72];
  int z = blockIdx.z;
  const u16* W = (z == 0) ? wqb : (z == 1 ? wkb : wvb);
  const float* bias = (z == 0) ? bq : (z == 1 ? bk : bv);
  int n0 = blockIdx.x * 128;
  int m0 = blockIdx.y * 128;
  int tid = threadIdx.x;
  int lane = tid & 63, wv_ = tid >> 6;
  int wm = wv_ & 1, wn = wv_ >> 1;
  int mcol = lane & 15, quad = lane >> 4;
  int chunk = tid & 7, rbase = tid >> 3;

  f32x4 acc[4][4] = {};

  for (int k0 = 0; k0 < KDIM; k0 += 64) {
    __syncthreads();
#pragma unroll
    for (int r = 0; r < 4; ++r) {
      int row = rbase + r * 32;
      *(uint4*)&lds_a[row * 72 + chunk * 8] =
          *(const uint4*)&xb[(size_t)(m0 + row) * KDIM + k0 + chunk * 8];
      *(uint4*)&lds_b[row * 72 + chunk * 8] =
          *(const uint4*)&W[(size_t)(n0 + row) * KDIM + k0 + chunk * 8];
    }
    __syncthreads();
#pragma unroll
    for (int kc = 0; kc < 2; ++kc) {
      bf16x8 af[4], bfr[4];
#pragma unroll
      for (int i = 0; i < 4; i++)
        af[i] = *(const bf16x8*)&lds_a[(wm * 64 + i * 16 + mcol) * 72 + kc * 32 + quad * 8];
#pragma unroll
      for (int i = 0; i < 4; i++)
        bfr[i] = *(const bf16x8*)&lds_b[(wn * 64 + i * 16 + mcol) * 72 + kc * 32 + quad * 8];
#pragma unroll
      for (int i = 0; i < 4; i++)
#pragma unroll
        for (int j = 0; j < 4; j++)
          acc[i][j] = __builtin_amdgcn_mfma_f32_16x16x32_bf16(af[i], bfr[j], acc[i][j], 0, 0, 0);
    }
  }

#pragma unroll
  for (int i = 0; i < 4; i++) {
    int rowb = m0 + wm * 64 + i * 16 + quad * 4;
    int b = rowb / TT;
    int tt0 = rowb - b * TT;       // token (key), multiple of 4, tt0&15 == quad*4
#pragma unroll
    for (int j = 0; j < 4; j++) {
      int col = n0 + wn * 64 + j * 16 + mcol;
      int h = col >> 6, d = col & 63;
      float bb_ = bias[col];
      size_t bhoff = (size_t)(b * NH + h) * (TT * HD);
      if (z == 2) {
        ushort4 pk;
        pk.x = f2bf(acc[i][j][0] + bb_);
        pk.y = f2bf(acc[i][j][1] + bb_);
        pk.z = f2bf(acc[i][j][2] + bb_);
        pk.w = f2bf(acc[i][j][3] + bb_);
        *(ushort4*)&vo[bhoff + (size_t)(tt0 >> 4) * 1024 + d * 16 + (tt0 & 15)] = pk;
      } else if (z == 1) {
        size_t base = bhoff + (size_t)(tt0 >> 4) * 1024 + (d >> 5) * 512 + (d & 31);
#pragma unroll
        for (int r = 0; r < 4; r++)
          ko[base + ((tt0 & 15) + r) * 32] = f2bf(acc[i][j][r] + bb_);
      } else {
#pragma unroll
        for (int r = 0; r < 4; r++)
          qo[bhoff + (size_t)(tt0 + r) * HD + d] = f2bf((acc[i][j][r] + bb_) * QSCALE);
      }
    }
  }
}

// ------- fused masked attention: 4 strips/wave, 2-way K-split per block ------
// 960 blocks x 128 thr (2 waves). Both waves own the SAME 4 q-strips; wave w
// processes kt tiles [w*10, w*10+10). Fixed m=0 makes partial O / rsum
// additive: wave 1 dumps accumulators to LDS once, one barrier, wave 0
// combines + stores. 34 strip-steps per kt-pair per wave -- fully balanced.
struct Strip {
  bf16x8 qf0, qf1;
  f32x4 o0, o1, o2, o3;
  f32x4 racc;   // ones-row MFMA accumulator: racc[0] = softmax denominator
};

__device__ __forceinline__ void strip_step(
    Strip& S, bf16x8 kf0, bf16x8 kf1,
    s16x4 vf0, s16x4 vf1, s16x4 vf2, s16x4 vf3,
    bool maskg, int mcol, int quad)
{
  f32x4 st = {0.f, 0.f, 0.f, 0.f};
  st = __builtin_amdgcn_mfma_f32_16x16x32_bf16(kf0, S.qf0, st, 0, 0, 0);
  st = __builtin_amdgcn_mfma_f32_16x16x32_bf16(kf1, S.qf1, st, 0, 0, 0);
  float p0 = __builtin_amdgcn_exp2f(st[0]);
  float p1 = __builtin_amdgcn_exp2f(st[1]);
  float p2 = __builtin_amdgcn_exp2f(st[2]);
  float p3 = __builtin_amdgcn_exp2f(st[3]);
  if (maskg) {
    int j0 = quad * 4;
    p0 = (j0 + 0 > mcol) ? 0.f : p0;
    p1 = (j0 + 1 > mcol) ? 0.f : p1;
    p2 = (j0 + 2 > mcol) ? 0.f : p2;
    p3 = (j0 + 3 > mcol) ? 0.f : p3;
  }
  u32 b0 = __builtin_bit_cast(u32, p0) + 0x8000u;
  u32 b1 = __builtin_bit_cast(u32, p1) + 0x8000u;
  u32 b2 = __builtin_bit_cast(u32, p2) + 0x8000u;
  u32 b3 = __builtin_bit_cast(u32, p3) + 0x8000u;
  uint2 pk;
  pk.x = __builtin_amdgcn_perm(b1, b0, 0x07060302u);
  pk.y = __builtin_amdgcn_perm(b3, b2, 0x07060302u);
  s16x4 pf = __builtin_bit_cast(s16x4, pk);
  const s16x4 ones = {0x3F80, 0x3F80, 0x3F80, 0x3F80};  // bf16 1.0 x4
  S.racc = mfma16b(ones, pf, S.racc);
  S.o0 = mfma16b(vf0, pf, S.o0);
  S.o1 = mfma16b(vf1, pf, S.o1);
  S.o2 = mfma16b(vf2, pf, S.o2);
  S.o3 = mfma16b(vf3, pf, S.o3);
}

#define OSTR 68   // padded f32 row stride for combine staging (bank stagger)

__global__ __launch_bounds__(128) void attn(
    const u16* __restrict__ q, const u16* __restrict__ kg,
    const u16* __restrict__ vg, u16* __restrict__ y)
{
  __shared__ float lds_o[4][16 * OSTR];
  __shared__ float lds_r[64];

  int tid = threadIdx.x;
  int lane = tid & 63, w = tid >> 6;   // w = K-half owner
  int mcol = lane & 15, quad = lane >> 4;
  int gid = blockIdx.x;
  int c = gid & 7;              // XCD (round-robin dispatch heuristic)
  int idx = gid >> 3;           // 0..119
  int sub = idx / 40;           // 0..2  -> 3 bh per XCD (K/V resident in L2)
  int s = idx - sub * 40;       // 0..39
  int bh = c * 3 + sub;
  int hb = s >> 3;              // 0..4  (512-row span)
  int r = s & 7;                // light local strip; heavy local = 7-r
  int b = bh / NH, h = bh - b * NH;
  const u16* qp = q + (size_t)bh * TT * HD;
  const u16* kp = kg + (size_t)bh * TT * HD;
  const u16* vp = vg + (size_t)bh * TT * HD;

  int base = hb * 512;
  int rh = 7 - r;
  int qr[4];
  qr[0] = base + r * 16;              // L1 (half 0 of 256-tile)
  qr[1] = base + 128 + rh * 16;       // H1 (half 1)
  qr[2] = base + 256 + r * 16;        // L2
  qr[3] = base + 384 + rh * 16;       // H2

  Strip S[4];
#pragma unroll
  for (int i = 0; i < 4; ++i) {
    S[i].qf0 = *(const bf16x8*)&qp[(size_t)(qr[i] + mcol) * HD + quad * 8];
    S[i].qf1 = *(const bf16x8*)&qp[(size_t)(qr[i] + mcol) * HD + 32 + quad * 8];
    S[i].o0 = {0.f, 0.f, 0.f, 0.f};
    S[i].o1 = {0.f, 0.f, 0.f, 0.f};
    S[i].o2 = {0.f, 0.f, 0.f, 0.f};
    S[i].o3 = {0.f, 0.f, 0.f, 0.f};
    S[i].racc = {0.f, 0.f, 0.f, 0.f};
  }

  int koff = mcol * 32 + quad * 8;  // u16 offset in K group (b128, coalesced)
  int voff = mcol * 16 + quad * 4;  // u16 offset in V df-slab (b64, coalesced)

  for (int kt = w * 10; kt < w * 10 + 10; ++kt) {
    const u16* ktb = kp + kt * (128 * HD);
    const u16* vtb = vp + kt * (128 * HD);
    if ((kt & 1) == 0) {
      // even tile: heavy strips full 8 groups; light strips groups 0..r
#pragma unroll
      for (int g = 0; g < 8; ++g) {
        bf16x8 kf0 = *(const bf16x8*)&ktb[g * 1024 + koff];
        bf16x8 kf1 = *(const bf16x8*)&ktb[g * 1024 + 512 + koff];
        s16x4 vf0 = *(const s16x4*)&vtb[g * 1024 + 0 * 256 + voff];
        s16x4 vf1 = *(const s16x4*)&vtb[g * 1024 + 1 * 256 + voff];
        s16x4 vf2 = *(const s16x4*)&vtb[g * 1024 + 2 * 256 + voff];
        s16x4 vf3 = *(const s16x4*)&vtb[g * 1024 + 3 * 256 + voff];
        strip_step(S[1], kf0, kf1, vf0, vf1, vf2, vf3, false, mcol, quad);
        strip_step(S[3], kf0, kf1, vf0, vf1, vf2, vf3, false, mcol, quad);
        if (g <= r) {
          bool mg = (g == r);
          strip_step(S[0], kf0, kf1, vf0, vf1, vf2, vf3, mg, mcol, quad);
          strip_step(S[2], kf0, kf1, vf0, vf1, vf2, vf3, mg, mcol, quad);
        }
      }
    } else {
      // odd tile: heavy strips groups 0..rh (partial at rh); light strips skip
      for (int g = 0; g <= rh; ++g) {
        bf16x8 kf0 = *(const bf16x8*)&ktb[g * 1024 + koff];
        bf16x8 kf1 = *(const bf16x8*)&ktb[g * 1024 + 512 + koff];
        s16x4 vf0 = *(const s16x4*)&vtb[g * 1024 + 0 * 256 + voff];
        s16x4 vf1 = *(const s16x4*)&vtb[g * 1024 + 1 * 256 + voff];
        s16x4 vf2 = *(const s16x4*)&vtb[g * 1024 + 2 * 256 + voff];
        s16x4 vf3 = *(const s16x4*)&vtb[g * 1024 + 3 * 256 + voff];
        bool mg = (g == rh);
        strip_step(S[1], kf0, kf1, vf0, vf1, vf2, vf3, mg, mcol, quad);
        strip_step(S[3], kf0, kf1, vf0, vf1, vf2, vf3, mg, mcol, quad);
      }
    }
  }

  // ---- combine the two K-halves through LDS (partials are additive, m=0) ----
  if (w == 1) {
#pragma unroll
    for (int i = 0; i < 4; ++i) {
      f32x4 oo[4] = {S[i].o0, S[i].o1, S[i].o2, S[i].o3};
#pragma unroll
      for (int df = 0; df < 4; ++df)
        *(f32x4*)&lds_o[i][mcol * OSTR + df * 16 + quad * 4] = oo[df];
      if (quad == 0) lds_r[i * 16 + mcol] = S[i].racc[0];
    }
  }
  __syncthreads();
  if (w == 0) {
#pragma unroll
    for (int i = 0; i < 4; ++i) {
      float denom = S[i].racc[0] + lds_r[i * 16 + mcol];
      float inv = 1.0f / denom;
      f32x4 oo[4] = {S[i].o0, S[i].o1, S[i].o2, S[i].o3};
      size_t yrow = ((size_t)(b * TT + qr[i] + mcol)) * CC + h * HD;
#pragma unroll
      for (int df = 0; df < 4; ++df) {
        f32x4 other = *(const f32x4*)&lds_o[i][mcol * OSTR + df * 16 + quad * 4];
        ushort4 pk;
        pk.x = f2bf((oo[df][0] + other[0]) * inv);
        pk.y = f2bf((oo[df][1] + other[1]) * inv);
        pk.z = f2bf((oo[df][2] + other[2]) * inv);
        pk.w = f2bf((oo[df][3] + other[3]) * inv);
        *(ushort4*)&y[yrow + df * 16 + quad * 4] = pk;
      }
    }
  }
}

// ---------------- output projection GEMM ----------------
__global__ __launch_bounds__(256) void gemm_out(
    const u16* __restrict__ yb, const u16* __restrict__ wpb,
    const float* __restrict__ bp, float* __restrict__ out)
{
  __shared__ __align__(16) u16 lds_a[128 * 72];
  __shared__ __align__(16) u16 lds_b[128 * 72];
  int n0 = blockIdx.x * 128;
  int m0 = blockIdx.y * 128;
  int tid = threadIdx.x;
  int lane = tid & 63, wv_ = tid >> 6;
  int wm = wv_ & 1, wn = wv_ >> 1;
  int mcol = lane & 15, quad = lane >> 4;
  int chunk = tid & 7, rbase = tid >> 3;

  f32x4 acc[4][4] = {};

  for (int k0 = 0; k0 < KDIM; k0 += 64) {
    __syncthreads();
#pragma unroll
    for (int r = 0; r < 4; ++r) {
      int row = rbase + r * 32;
      *(uint4*)&lds_a[row * 72 + chunk * 8] =
          *(const uint4*)&yb[(size_t)(m0 + row) * KDIM + k0 + chunk * 8];
      *(uint4*)&lds_b[row * 72 + chunk * 8] =
          *(const uint4*)&wpb[(size_t)(n0 + row) * KDIM + k0 + chunk * 8];
    }
    __syncthreads();
#pragma unroll
    for (int kc = 0; kc < 2; ++kc) {
      bf16x8 af[4], bfr[4];
#pragma unroll
      for (int i = 0; i < 4; i++)
        af[i] = *(const bf16x8*)&lds_a[(wm * 64 + i * 16 + mcol) * 72 + kc * 32 + quad * 8];
#pragma unroll
      for (int i = 0; i < 4; i++)
        bfr[i] = *(const bf16x8*)&lds_b[(wn * 64 + i * 16 + mcol) * 72 + kc * 32 + quad * 8];
#pragma unroll
      for (int i = 0; i < 4; i++)
#pragma unroll
        for (int j = 0; j < 4; j++)
          acc[i][j] = __builtin_amdgcn_mfma_f32_16x16x32_bf16(af[i], bfr[j], acc[i][j], 0, 0, 0);
    }
  }

#pragma unroll
  for (int i = 0; i < 4; i++) {
    int row0 = m0 + wm * 64 + i * 16 + quad * 4;
#pragma unroll
    for (int j = 0; j < 4; j++) {
      int col = n0 + wn * 64 + j * 16 + mcol;
      float bb_ = bp[col];
#pragma unroll
      for (int r = 0; r < 4; r++)
        out[(size_t)(row0 + r) * CC + col] = acc[i][j][r] + bb_;
    }
  }
}

extern "C" void kernel_launch(void* const* d_in, const int* in_sizes, int n_in,
                              void* d_out, int out_size, void* d_ws, size_t ws_size,
                              hipStream_t stream) {
  const float* x  = (const float*)d_in[0];
  const float* Wk = (const float*)d_in[1];
  const float* bk = (const float*)d_in[2];
  const float* Wq = (const float*)d_in[3];
  const float* bq = (const float*)d_in[4];
  const float* Wv = (const float*)d_in[5];
  const float* bv = (const float*)d_in[6];
  const float* Wp = (const float*)d_in[7];
  const float* bp = (const float*)d_in[8];
  float* out = (float*)d_out;

  char* ws = (char*)d_ws;
  size_t off = 0;
  auto alloc = [&](size_t bytes) {
    void* p = ws + off;
    off += (bytes + 255) & ~(size_t)255;
    return p;
  };
  const size_t NX = (size_t)2 * TT * CC;
  const size_t NW = (size_t)CC * CC;
  u16* xb  = (u16*)alloc(NX * 2);
  u16* wqb = (u16*)alloc(NW * 2);
  u16* wkb = (u16*)alloc(NW * 2);
  u16* wvb = (u16*)alloc(NW * 2);
  u16* wpb = (u16*)alloc(NW * 2);
  u16* qws = (u16*)alloc(NX * 2);
  u16* kws = (u16*)alloc(NX * 2);
  u16* vgw = (u16*)alloc(NX * 2);
  u16* yws = (u16*)alloc(NX * 2);

  int nx4 = (int)(NX / 4), nw4 = (int)(NW / 4);
  convall<<<dim3((nx4 + 255) / 256, 5), 256, 0, stream>>>(
      x, Wq, Wk, Wv, Wp, xb, wqb, wkb, wvb, wpb, nx4, nw4);

  gemm_qkv<<<dim3(6, 40, 3), 256, 0, stream>>>(xb, wqb, wkb, wvb, bq, bk, bv,
                                               qws, kws, vgw);
  attn<<<dim3(960), 128, 0, stream>>>(qws, kws, vgw, yws);
  gemm_out<<<dim3(6, 40), 256, 0, stream>>>(yws, wpb, bp, out);
}